// Round 1
// baseline (235.418 us; speedup 1.0000x reference)
//
#include <hip/hip_runtime.h>
#include <hip/hip_bf16.h>
#include <cstdint>

// Problem constants
#define S_FRAMES 128
#define HW       50176            // 224*224
#define NGRP     12544            // HW/4 float4 groups per frame
#define GDIM     48
#define VWORDS   3456             // 48^3 / 32 bits
#define NBINS    4096
#define CAP      512
#define KSEL     16
#define VBW      1568             // valid-nibble words per frame (NGRP/8)

// compact greedy
#define UWC      512u             // compact stride (words) per frame, zero-padded
#define UCAP_BITS 16384u          // max compact bits handled (streaming tier)
#define RQ       9                // register-tier uint4 per slice (288 words)

// workspace layout (in 32-bit words)
#define OCCA_OFF  0u                          // 128 * 3456 words (part 0 bitmaps)
#define OCCB_OFF  (128u*3456u)                // 442368: part 1 bitmaps
#define MM_OFF    (2u*128u*3456u)             // 884736: 128 slots x 8 floats (min3,max3)
#define CTR_OFF   (MM_OFF + 1024u)            // last-block-done counter
#define UNI_OFF   (CTR_OFF + 16u)             // union bitmap, 3456 words
#define CMP_OFF   (UNI_OFF + VWORDS)          // 128 x 512 compact bitmaps (16B aligned)
#define VB_OFF    (CMP_OFF + 128u*UWC)        // 128 x 1568 words valid nibbles

// ---------------------------------------------------------------------------
// Pass A (fused): exact per-frame median (quantile 0.5 linear) via histogram
// select, THEN validity nibbles + per-frame min/max in a third (L2-hot) conf
// pass that also reads wp once. Per-frame MM slot is private (no atomics, no
// pre-zero). Also zeroes UNI chunk + last-block counter (consumed 1-2 kernels
// later, so kernel boundaries order the zeroing).
// ---------------------------------------------------------------------------
__global__ __launch_bounds__(1024) void fused_stats_kernel(const float* __restrict__ conf,
                                                           const float* __restrict__ wp,
                                                           unsigned* __restrict__ ws) {
    const int s = blockIdx.x;
    const int tid = threadIdx.x;
    const int lane = tid & 63, wid = tid >> 6;
    const float4* c4 = (const float4*)(conf + (size_t)s * HW);

    // zero union chunk (128*27 == 3456) + counter
    if (tid < 27) ws[UNI_OFF + (unsigned)s * 27u + tid] = 0u;
    if (s == 0 && tid == 31) ws[CTR_OFF] = 0u;

    __shared__ unsigned hist[NBINS];
    __shared__ unsigned vbw[VBW];
    __shared__ unsigned wtot[16];
    __shared__ unsigned woff[16];
    __shared__ float    list[CAP];
    __shared__ unsigned cnt;
    __shared__ int      rbin[2];
    __shared__ unsigned rcum[2];
    __shared__ float    ab[2];
    __shared__ float    medsh;
    __shared__ float    red[16][6];

    for (int b = tid; b < NBINS; b += 1024) hist[b] = 0;
    for (int w = tid; w < VBW; w += 1024) vbw[w] = 0;
    if (tid == 0) cnt = 0;
    __syncthreads();

    // ---- pass 1: histogram (HBM-cold conf read; stays L2-resident) ----
    for (int g = tid; g < NGRP; g += 1024) {
        float4 v = c4[g];
        int b0 = min(max((int)(v.x * 4096.0f), 0), NBINS - 1);
        int b1 = min(max((int)(v.y * 4096.0f), 0), NBINS - 1);
        int b2 = min(max((int)(v.z * 4096.0f), 0), NBINS - 1);
        int b3 = min(max((int)(v.w * 4096.0f), 0), NBINS - 1);
        atomicAdd(&hist[b0], 1u); atomicAdd(&hist[b1], 1u);
        atomicAdd(&hist[b2], 1u); atomicAdd(&hist[b3], 1u);
    }
    __syncthreads();

    unsigned chunk = hist[tid * 4] + hist[tid * 4 + 1] + hist[tid * 4 + 2] + hist[tid * 4 + 3];
    unsigned x = chunk;
#pragma unroll
    for (int m = 1; m < 64; m <<= 1) {
        unsigned y = (unsigned)__shfl_up((int)x, m);
        if (lane >= m) x += y;
    }
    if (lane == 63) wtot[wid] = x;
    __syncthreads();
    if (tid < 16) {
        unsigned acc = 0;
        for (int w = 0; w < tid; w++) acc += wtot[w];
        woff[tid] = acc;
    }
    __syncthreads();
    unsigned excl = x - chunk + woff[wid];

    const unsigned R0 = 25087u, R1 = 25088u;  // 0.5*(50176-1) = 25087.5
#pragma unroll
    for (int r = 0; r < 2; r++) {
        unsigned rr = r ? R1 : R0;
        if (rr >= excl && rr < excl + chunk) {
            unsigned cum = excl;
            for (int j = 0; j < 4; j++) {
                unsigned h = hist[tid * 4 + j];
                if (rr < cum + h) { rbin[r] = tid * 4 + j; rcum[r] = cum; break; }
                cum += h;
            }
        }
    }
    __syncthreads();

    const int blo = rbin[0], bhi = rbin[1];
    const unsigned cumLo = rcum[0];

    // ---- pass 2 (L2-hot): collect candidates in the rank bins ----
    for (int g = tid; g < NGRP; g += 1024) {
        float4 v = c4[g];
        float vv[4] = {v.x, v.y, v.z, v.w};
#pragma unroll
        for (int j = 0; j < 4; j++) {
            int b = min(max((int)(vv[j] * 4096.0f), 0), NBINS - 1);
            if (b >= blo && b <= bhi) {
                unsigned pos = atomicAdd(&cnt, 1u);
                if (pos < CAP) list[pos] = vv[j];
            }
        }
    }
    __syncthreads();

    const int n = (int)min(cnt, (unsigned)CAP);
    const int r0 = (int)(R0 - cumLo), r1 = (int)(R1 - cumLo);
    for (int e = tid; e < n; e += 1024) {
        float xx = list[e];
        int rank = 0;
        for (int j = 0; j < n; j++) {
            float y = list[j];
            rank += (y < xx) || (y == xx && j < e);   // stable rank
        }
        if (rank == r0) ab[0] = xx;
        if (rank == r1) ab[1] = xx;
    }
    __syncthreads();
    if (tid == 0) medsh = 0.5f * ab[0] + 0.5f * ab[1];
    __syncthreads();
    const float med = medsh;

    // ---- pass 3 (conf L2-hot + wp HBM): validity nibbles + frame min/max ----
    const size_t base = (size_t)s * HW;
    const float4* wp4 = (const float4*)(wp + base * 3);
    const float BIG = 3.402823466e38f;
    float mnx = BIG, mny = BIG, mnz = BIG;
    float mxx = -BIG, mxy = -BIG, mxz = -BIG;

    for (int g = tid; g < NGRP; g += 1024) {
        float4 v = c4[g];
        float cc[4] = {v.x, v.y, v.z, v.w};
        unsigned nib = 0;
#pragma unroll
        for (int j = 0; j < 4; j++) {
            bool val = (cc[j] > 0.1f) && (cc[j] >= med);
            nib |= (val ? 1u : 0u) << j;
        }
        if (nib) {
            atomicOr(&vbw[g >> 3], nib << ((g & 7) * 4));
            const float4* wg = wp4 + (size_t)g * 3;
            float4 a = wg[0], bb = wg[1], d = wg[2];
            float px[4] = {a.x, a.w, bb.z, d.y};
            float py[4] = {a.y, bb.x, bb.w, d.z};
            float pz[4] = {a.z, bb.y, d.x, d.w};
#pragma unroll
            for (int j = 0; j < 4; j++) {
                if ((nib >> j) & 1u) {
                    mnx = fminf(mnx, px[j]); mny = fminf(mny, py[j]); mnz = fminf(mnz, pz[j]);
                    mxx = fmaxf(mxx, px[j]); mxy = fmaxf(mxy, py[j]); mxz = fmaxf(mxz, pz[j]);
                }
            }
        }
    }

#pragma unroll
    for (int m = 32; m >= 1; m >>= 1) {
        mnx = fminf(mnx, __shfl_xor(mnx, m)); mny = fminf(mny, __shfl_xor(mny, m));
        mnz = fminf(mnz, __shfl_xor(mnz, m));
        mxx = fmaxf(mxx, __shfl_xor(mxx, m)); mxy = fmaxf(mxy, __shfl_xor(mxy, m));
        mxz = fmaxf(mxz, __shfl_xor(mxz, m));
    }
    if (lane == 0) {
        red[wid][0] = mnx; red[wid][1] = mny; red[wid][2] = mnz;
        red[wid][3] = mxx; red[wid][4] = mxy; red[wid][5] = mxz;
    }
    __syncthreads();
    if (tid == 0) {
        float r0f = red[0][0], r1f = red[0][1], r2f = red[0][2];
        float r3f = red[0][3], r4f = red[0][4], r5f = red[0][5];
        for (int w = 1; w < 16; w++) {
            r0f = fminf(r0f, red[w][0]); r1f = fminf(r1f, red[w][1]); r2f = fminf(r2f, red[w][2]);
            r3f = fmaxf(r3f, red[w][3]); r4f = fmaxf(r4f, red[w][4]); r5f = fmaxf(r5f, red[w][5]);
        }
        float* slot = (float*)(ws + MM_OFF) + (size_t)s * 8;
        slot[0] = r0f; slot[1] = r1f; slot[2] = r2f;
        slot[3] = r3f; slot[4] = r4f; slot[5] = r5f;
    }
    // store valid nibbles (fully overwritten; no pre-zero dependence)
    for (int w = tid; w < VBW; w += 1024) ws[VB_OFF + (unsigned)s * 1568u + w] = vbw[w];
}

// ---------------------------------------------------------------------------
// Pass B: per-frame voxel occupancy + fused union. grid 256 (2/frame) x 1024
// (1024 thr => 4 waves/SIMD: latency hiding for the wp gather; was 2).
// Consumes valid nibbles. Stores half-frame plane; ORs nonzero words into UNI.
// ---------------------------------------------------------------------------
__global__ __launch_bounds__(1024) void voxel_kernel(const float* __restrict__ wp,
                                                     unsigned* __restrict__ ws) {
    const int s = blockIdx.x >> 1;
    const int part = blockIdx.x & 1;
    const int tid = threadIdx.x;

    __shared__ unsigned bm[VWORDS];
    __shared__ float prm[4];  // pmx,pmy,pmz,vs
    for (int w = tid; w < VWORDS; w += 1024) bm[w] = 0;

    if (tid < 64) {
        const float* m0 = (const float*)(ws + MM_OFF) + (size_t)tid * 8;
        const float* m1 = m0 + 64 * 8;
        float mnx = fminf(m0[0], m1[0]), mny = fminf(m0[1], m1[1]), mnz = fminf(m0[2], m1[2]);
        float mxx = fmaxf(m0[3], m1[3]), mxy = fmaxf(m0[4], m1[4]), mxz = fmaxf(m0[5], m1[5]);
#pragma unroll
        for (int m = 32; m >= 1; m >>= 1) {
            mnx = fminf(mnx, __shfl_xor(mnx, m)); mny = fminf(mny, __shfl_xor(mny, m));
            mnz = fminf(mnz, __shfl_xor(mnz, m));
            mxx = fmaxf(mxx, __shfl_xor(mxx, m)); mxy = fmaxf(mxy, __shfl_xor(mxy, m));
            mxz = fmaxf(mxz, __shfl_xor(mxz, m));
        }
        if (tid == 0) {
            prm[0] = mnx; prm[1] = mny; prm[2] = mnz;
            prm[3] = fminf(mxx - mnx, fminf(mxy - mny, mxz - mnz)) / 20.0f;  // VOXEL_LAMBDA
        }
    }
    __syncthreads();

    const float pmx = prm[0], pmy = prm[1], pmz = prm[2], vs = prm[3];
    const size_t base = (size_t)s * HW;
    const float4* w4 = (const float4*)(wp + base * 3);
    const unsigned* vb = ws + VB_OFF + (unsigned)s * 1568u;

#pragma unroll 1
    for (int k = 0; k < 7; k++) {
        int gl = k * 1024 + tid;                       // local group in half
        if (gl >= 6272) break;
        int g = part * 6272 + gl;
        unsigned nib = (vb[g >> 3] >> ((g & 7) * 4)) & 0xFu;
        if (!nib) continue;
        const float4* wg = w4 + (size_t)g * 3;
        float4 a = wg[0], b = wg[1], d = wg[2];
        float px[4] = {a.x, a.w, b.z, d.y};
        float py[4] = {a.y, b.x, b.w, d.z};
        float pz[4] = {a.z, b.y, d.x, d.w};
#pragma unroll
        for (int j = 0; j < 4; j++) {
            if ((nib >> j) & 1u) {
                int ix = min(max((int)floorf((px[j] - pmx) / vs), 0), GDIM - 1);
                int iy = min(max((int)floorf((py[j] - pmy) / vs), 0), GDIM - 1);
                int iz = min(max((int)floorf((pz[j] - pmz) / vs), 0), GDIM - 1);
                int vid = (ix * GDIM + iy) * GDIM + iz;
                atomicOr(&bm[vid >> 5], 1u << (vid & 31));
            }
        }
    }
    __syncthreads();

    unsigned* occ = ws + (part ? OCCB_OFF : OCCA_OFF) + (unsigned)s * VWORDS;
    for (int w = tid; w < VWORDS; w += 1024) {
        unsigned v = bm[w];
        occ[w] = v;
        if (v) atomicOr(&ws[UNI_OFF + w], v);   // fused union (UNI zeroed in pass A)
    }
}

// ---------------------------------------------------------------------------
// Pass C (fused): remap each frame's bitmap into compact-id space, then the
// LAST block to finish (device-scope counter, release/acquire fences) runs
// the compact greedy in-place. Removes a kernel launch + FLAG/UW indirection.
// ---------------------------------------------------------------------------
__global__ __launch_bounds__(1024, 1) void remap_greedy_kernel(unsigned* __restrict__ ws,
                                                               float* __restrict__ out) {
    const int f = blockIdx.x;
    const int tid = threadIdx.x;
    const int lane = tid & 63, wid = tid >> 6;

    __shared__ unsigned uni[VWORDS];
    __shared__ unsigned short basew[VWORDS];
    __shared__ unsigned cbm[UWC];
    __shared__ unsigned wtot[16];
    __shared__ unsigned woff[16];
    __shared__ unsigned Ush;
    __shared__ unsigned rank_sh;
    // greedy state
    __shared__ unsigned cov[UWC];
    __shared__ int gains[S_FRAMES];
    __shared__ unsigned bestsh;

    for (int w = tid; w < VWORDS; w += 1024) uni[w] = ws[UNI_OFF + w];
    for (int w = tid; w < (int)UWC; w += 1024) cbm[w] = 0;
    __syncthreads();

    // popc prefix scan: 4 words/thread (4*1024 >= 3456)
    const int w0 = tid * 4;
    unsigned chunk = 0;
#pragma unroll
    for (int j = 0; j < 4; j++) { int w = w0 + j; if (w < VWORDS) chunk += __popc(uni[w]); }
    unsigned x = chunk;
#pragma unroll
    for (int m = 1; m < 64; m <<= 1) {
        unsigned y = (unsigned)__shfl_up((int)x, m);
        if (lane >= m) x += y;
    }
    if (lane == 63) wtot[wid] = x;
    __syncthreads();
    if (tid < 16) {
        unsigned acc = 0;
        for (int w = 0; w < tid; w++) acc += wtot[w];
        woff[tid] = acc;
    }
    __syncthreads();
    unsigned running = x - chunk + woff[wid];
#pragma unroll
    for (int j = 0; j < 4; j++) {
        int w = w0 + j;
        if (w < VWORDS) { basew[w] = (unsigned short)running; running += __popc(uni[w]); }
    }
    if (tid == 1023) Ush = running;
    __syncthreads();
    const unsigned U = Ush;
    if (U > UCAP_BITS) return;            // out of supported range (never for this input)

    const unsigned* pA = ws + OCCA_OFF + (unsigned)f * VWORDS;
    const unsigned* pB = ws + OCCB_OFF + (unsigned)f * VWORDS;
    for (int w = tid; w < VWORDS; w += 1024) {
        unsigned v = pA[w] | pB[w];
        if (!v) continue;
        unsigned uw = uni[w], b0 = basew[w];
        while (v) {
            int b = __ffs(v) - 1; v &= v - 1;
            unsigned cid = b0 + (unsigned)__popc(uw & ((1u << b) - 1u));
            atomicOr(&cbm[cid >> 5], 1u << (cid & 31));
        }
    }
    __syncthreads();
    for (int w = tid; w < (int)UWC; w += 1024) ws[CMP_OFF + (unsigned)f * UWC + w] = cbm[w];

    // ---- last-block-done handoff ----
    __syncthreads();                       // all CMP stores issued+drained (vmcnt in barrier)
    if (tid == 0) {
        __threadfence();                   // release: make CMP visible device-wide
        rank_sh = atomicAdd(&ws[CTR_OFF], 1u);
    }
    __syncthreads();
    if (rank_sh != (unsigned)(S_FRAMES - 1)) return;
    __threadfence();                       // acquire: invalidate stale cached CMP lines

    // ---- compact greedy (runs in the last block only) ----
    const int gf = tid >> 3, sl = tid & 7;
    const unsigned UW = (U + 31u) >> 5;    // <= 512

    for (int w = tid; w < (int)UWC; w += 1024) cov[w] = 0u;
    bool selF = false;
    int best = -1;

    if (UW <= 32u * RQ) {
        // ---------------- register tier ----------------
        uint4 occw[RQ];
        const uint4* my4 = (const uint4*)(ws + CMP_OFF + (unsigned)gf * UWC) + sl * RQ;
#pragma unroll
        for (int j = 0; j < RQ; j++) occw[j] = my4[j];
        __syncthreads();

        for (int it = 0; it < KSEL; it++) {
            if (best >= 0 && gf == best) {         // owners fold cov from regs
#pragma unroll
                for (int j = 0; j < RQ; j++) {
                    int w = (sl * RQ + j) * 4;
                    cov[w] |= occw[j].x; cov[w + 1] |= occw[j].y;
                    cov[w + 2] |= occw[j].z; cov[w + 3] |= occw[j].w;
                }
            }
            __syncthreads();                      // B1: cov updated
            int g = 0;
#pragma unroll
            for (int j = 0; j < RQ; j++) {
                int w = (sl * RQ + j) * 4;
                g += __popc(occw[j].x & ~cov[w]) + __popc(occw[j].y & ~cov[w + 1])
                   + __popc(occw[j].z & ~cov[w + 2]) + __popc(occw[j].w & ~cov[w + 3]);
            }
            g += __shfl_xor(g, 1); g += __shfl_xor(g, 2); g += __shfl_xor(g, 4);
            if (sl == 0) gains[gf] = selF ? -1 : g;
            __syncthreads();                      // B2: gains ready
            if (tid < 64) {
                int g1 = gains[tid], g2 = gains[tid + 64];
                unsigned k1 = (g1 < 0) ? 0u : (((unsigned)g1 << 7) | (unsigned)(127 - tid));
                unsigned k2 = (g2 < 0) ? 0u : (((unsigned)g2 << 7) | (unsigned)(63 - tid));
                unsigned k = max(k1, k2);
#pragma unroll
                for (int m = 32; m >= 1; m >>= 1) k = max(k, (unsigned)__shfl_xor((int)k, m));
                if (tid == 0) {
                    bestsh = k;
                    out[it] = (float)(127 - (int)(k & 127u));
                    out[KSEL + it] = (float)(k >> 7);
                }
            }
            __syncthreads();                      // B3: best visible
            best = 127 - (int)(bestsh & 127u);
            if (gf == best) selF = true;
        }
        if (gf == best) {
#pragma unroll
            for (int j = 0; j < RQ; j++) {
                int w = (sl * RQ + j) * 4;
                cov[w] |= occw[j].x; cov[w + 1] |= occw[j].y;
                cov[w + 2] |= occw[j].z; cov[w + 3] |= occw[j].w;
            }
        }
        __syncthreads();
        if (gf == 0) {
            int t = 0;
#pragma unroll
            for (int j = 0; j < RQ; j++) {
                int w = (sl * RQ + j) * 4;
                t += __popc(cov[w]) + __popc(cov[w + 1]) + __popc(cov[w + 2]) + __popc(cov[w + 3]);
            }
            t += __shfl_xor(t, 1); t += __shfl_xor(t, 2); t += __shfl_xor(t, 4);
            if (sl == 0) out[2 * KSEL] = (float)t;
        }
    } else {
        // ---------------- streaming tier ----------------
        const int Q = (int)((UW + 31) >> 5);      // uint4 per slice
        const uint4* my4 = (const uint4*)(ws + CMP_OFF + (unsigned)gf * UWC) + sl * Q;
        __syncthreads();

        for (int it = 0; it < KSEL; it++) {
            if (best >= 0 && gf == best) {
                const uint4* b4 = (const uint4*)(ws + CMP_OFF + (unsigned)best * UWC) + sl * Q;
#pragma unroll 4
                for (int j = 0; j < Q; j++) {
                    uint4 o = b4[j];
                    int w = (sl * Q + j) * 4;
                    cov[w] |= o.x; cov[w + 1] |= o.y; cov[w + 2] |= o.z; cov[w + 3] |= o.w;
                }
            }
            __syncthreads();                      // B1
            int g = 0;
#pragma unroll 4
            for (int j = 0; j < Q; j++) {
                uint4 o = my4[j];
                int w = (sl * Q + j) * 4;
                g += __popc(o.x & ~cov[w]) + __popc(o.y & ~cov[w + 1])
                   + __popc(o.z & ~cov[w + 2]) + __popc(o.w & ~cov[w + 3]);
            }
            g += __shfl_xor(g, 1); g += __shfl_xor(g, 2); g += __shfl_xor(g, 4);
            if (sl == 0) gains[gf] = selF ? -1 : g;
            __syncthreads();                      // B2
            if (tid < 64) {
                int g1 = gains[tid], g2 = gains[tid + 64];
                unsigned k1 = (g1 < 0) ? 0u : (((unsigned)g1 << 7) | (unsigned)(127 - tid));
                unsigned k2 = (g2 < 0) ? 0u : (((unsigned)g2 << 7) | (unsigned)(63 - tid));
                unsigned k = max(k1, k2);
#pragma unroll
                for (int m = 32; m >= 1; m >>= 1) k = max(k, (unsigned)__shfl_xor((int)k, m));
                if (tid == 0) {
                    bestsh = k;
                    out[it] = (float)(127 - (int)(k & 127u));
                    out[KSEL + it] = (float)(k >> 7);
                }
            }
            __syncthreads();                      // B3
            best = 127 - (int)(bestsh & 127u);
            if (gf == best) selF = true;
        }
        if (gf == best) {
            const uint4* b4 = (const uint4*)(ws + CMP_OFF + (unsigned)best * UWC) + sl * Q;
#pragma unroll 4
            for (int j = 0; j < Q; j++) {
                uint4 o = b4[j];
                int w = (sl * Q + j) * 4;
                cov[w] |= o.x; cov[w + 1] |= o.y; cov[w + 2] |= o.z; cov[w + 3] |= o.w;
            }
        }
        __syncthreads();
        if (gf == 0) {
            int t = 0;
#pragma unroll 4
            for (int j = 0; j < Q; j++) {
                int w = (sl * Q + j) * 4;
                t += __popc(cov[w]) + __popc(cov[w + 1]) + __popc(cov[w + 2]) + __popc(cov[w + 3]);
            }
            t += __shfl_xor(t, 1); t += __shfl_xor(t, 2); t += __shfl_xor(t, 4);
            if (sl == 0) out[2 * KSEL] = (float)t;
        }
    }
}

extern "C" void kernel_launch(void* const* d_in, const int* in_sizes, int n_in,
                              void* d_out, int out_size, void* d_ws, size_t ws_size,
                              hipStream_t stream) {
    const float* wp   = (const float*)d_in[2];  // world_points [1,S,H,W,3]
    const float* conf = (const float*)d_in[3];  // world_points_conf [1,S,H,W]
    float* out = (float*)d_out;
    unsigned* ws = (unsigned*)d_ws;

    fused_stats_kernel<<<128, 1024, 0, stream>>>(conf, wp, ws);
    voxel_kernel<<<256, 1024, 0, stream>>>(wp, ws);
    remap_greedy_kernel<<<128, 1024, 0, stream>>>(ws, out);
}